// Round 1
// baseline (185.336 us; speedup 1.0000x reference)
//
#include <hip/hip_runtime.h>
#include <math.h>

#define B 32
#define H 8
#define C 64
#define L 1024
#define HC (H * C)            // 512
#define K 6
#define CHUNKS 32
#define ROWS_PER_CHUNK (HC / CHUNKS)  // 16

// ---------------------------------------------------------------------------
// Stage 1: partial sums of corr over (h,c) in 32 chunks of 16 rows each.
// grid = B*CHUNKS = 1024 blocks, 256 threads, float4 loads (fully coalesced).
// ---------------------------------------------------------------------------
__global__ __launch_bounds__(256) void partial_sum_kernel(
    const float* __restrict__ corr, float* __restrict__ partial) {
    int blk = blockIdx.x;                 // 0 .. B*CHUNKS-1
    int b = blk / CHUNKS;
    int chunk = blk % CHUNKS;
    int tid = threadIdx.x;                // 0..255, 4 floats each
    const float4* base =
        (const float4*)(corr + ((size_t)b * HC + (size_t)chunk * ROWS_PER_CHUNK) * L);
    float4 acc = make_float4(0.f, 0.f, 0.f, 0.f);
    for (int r = 0; r < ROWS_PER_CHUNK; ++r) {
        float4 v = base[r * (L / 4) + tid];
        acc.x += v.x; acc.y += v.y; acc.z += v.z; acc.w += v.w;
    }
    ((float4*)(partial + (size_t)blk * L))[tid] = acc;
}

// ---------------------------------------------------------------------------
// Stage 2: mean_value[b][l] = sum of 32 partials / 512.
// grid = B*L/256 = 128 blocks. Consecutive threads -> consecutive l: coalesced.
// ---------------------------------------------------------------------------
__global__ __launch_bounds__(256) void mean_kernel(
    const float* __restrict__ partial, float* __restrict__ mean_value) {
    int gid = blockIdx.x * 256 + threadIdx.x;   // 0 .. B*L-1
    int b = gid / L;
    int l = gid - b * L;
    float s = 0.f;
    for (int c = 0; c < CHUNKS; ++c)
        s += partial[((size_t)b * CHUNKS + c) * L + l];
    mean_value[gid] = s * (1.0f / HC);
}

// ---------------------------------------------------------------------------
// Stage 3: column mean over b, top-6 (tie-break: smaller index, like
// lax.top_k), then per-batch softmax over the 6 gathered weights.
// Single block of 1024 threads.
// ---------------------------------------------------------------------------
__global__ __launch_bounds__(1024) void topk_softmax_kernel(
    const float* __restrict__ mean_value,
    float* __restrict__ tmp_corr,       // [B][K]
    int* __restrict__ index_out) {      // [K]
    __shared__ float colmean[L];
    __shared__ float sval[1024];
    __shared__ int   sidx[1024];
    __shared__ int   sel[K];
    int t = threadIdx.x;

    float s = 0.f;
    for (int b = 0; b < B; ++b) s += mean_value[b * L + t];
    colmean[t] = s * (1.0f / B);
    __syncthreads();

    for (int k = 0; k < K; ++k) {
        sval[t] = colmean[t];
        sidx[t] = t;
        __syncthreads();
        for (int stride = 512; stride >= 1; stride >>= 1) {
            if (t < stride) {
                float v2 = sval[t + stride];
                int   i2 = sidx[t + stride];
                if (v2 > sval[t] || (v2 == sval[t] && i2 < sidx[t])) {
                    sval[t] = v2; sidx[t] = i2;
                }
            }
            __syncthreads();
        }
        if (t == 0) {
            sel[k] = sidx[0];
            colmean[sidx[0]] = -3.0e38f;   // remove from next round
        }
        __syncthreads();
    }

    if (t < K) index_out[t] = sel[t];
    if (t < B) {
        float w[K];
        float m = -3.0e38f;
        for (int k = 0; k < K; ++k) {
            w[k] = mean_value[t * L + sel[k]];
            m = fmaxf(m, w[k]);
        }
        float sum = 0.f;
        for (int k = 0; k < K; ++k) { w[k] = expf(w[k] - m); sum += w[k]; }
        float inv = 1.0f / sum;
        for (int k = 0; k < K; ++k) tmp_corr[t * K + k] = w[k] * inv;
    }
}

// ---------------------------------------------------------------------------
// Stage 4: out[b,h,c,l] = sum_k w[b,k] * values[b,h,c,(l+idx[k]) % L]
// One block per (b,h,c) row; row staged in LDS (4 KB); float4 in/out.
// LDS reads are stride-1 across lanes per k -> conflict-free.
// ---------------------------------------------------------------------------
__global__ __launch_bounds__(256) void agg_kernel(
    const float* __restrict__ values,
    const float* __restrict__ tmp_corr,
    const int* __restrict__ index,
    float* __restrict__ out) {
    __shared__ float row[L];
    __shared__ float w[K];
    __shared__ int   idx[K];
    int blk = blockIdx.x;                  // 0 .. B*H*C-1
    int b = blk / HC;
    int tid = threadIdx.x;

    ((float4*)row)[tid] = ((const float4*)(values + (size_t)blk * L))[tid];
    if (tid < K) { w[tid] = tmp_corr[b * K + tid]; idx[tid] = index[tid]; }
    __syncthreads();

    int l0 = tid * 4;
    float4 acc = make_float4(0.f, 0.f, 0.f, 0.f);
    for (int k = 0; k < K; ++k) {
        float wk = w[k];
        int base = l0 + idx[k];
        acc.x += wk * row[(base + 0) & (L - 1)];
        acc.y += wk * row[(base + 1) & (L - 1)];
        acc.z += wk * row[(base + 2) & (L - 1)];
        acc.w += wk * row[(base + 3) & (L - 1)];
    }
    ((float4*)(out + (size_t)blk * L))[tid] = acc;
}

// ---------------------------------------------------------------------------
extern "C" void kernel_launch(void* const* d_in, const int* in_sizes, int n_in,
                              void* d_out, int out_size, void* d_ws, size_t ws_size,
                              hipStream_t stream) {
    const float* values = (const float*)d_in[0];
    const float* corr   = (const float*)d_in[1];
    float* out = (float*)d_out;

    // workspace layout
    float* partial    = (float*)d_ws;                       // B*CHUNKS*L = 4 MiB
    float* mean_value = partial + (size_t)B * CHUNKS * L;   // B*L floats
    float* tmp_corr   = mean_value + (size_t)B * L;         // B*K floats
    int*   index      = (int*)(tmp_corr + B * K);           // K ints

    partial_sum_kernel<<<B * CHUNKS, 256, 0, stream>>>(corr, partial);
    mean_kernel<<<(B * L) / 256, 256, 0, stream>>>(partial, mean_value);
    topk_softmax_kernel<<<1, 1024, 0, stream>>>(mean_value, tmp_corr, index);
    agg_kernel<<<B * H * C, 256, 0, stream>>>(values, tmp_corr, index, out);
}

// Round 2
// 181.876 us; speedup vs baseline: 1.0190x; 1.0190x over previous
//
#include <hip/hip_runtime.h>
#include <math.h>

#define B 32
#define H 8
#define C 64
#define L 1024
#define HC (H * C)            // 512
#define K 6
#define CHUNKS 32
#define ROWS_PER_CHUNK (HC / CHUNKS)  // 16

// ---------------------------------------------------------------------------
// Stage 1: partial sums of corr over (h,c) in 32 chunks of 16 rows each.
// grid = B*CHUNKS = 1024 blocks, 256 threads, float4 loads (fully coalesced).
// ---------------------------------------------------------------------------
__global__ __launch_bounds__(256) void partial_sum_kernel(
    const float* __restrict__ corr, float* __restrict__ partial) {
    int blk = blockIdx.x;                 // 0 .. B*CHUNKS-1
    int b = blk / CHUNKS;
    int chunk = blk % CHUNKS;
    int tid = threadIdx.x;                // 0..255, 4 floats each
    const float4* base =
        (const float4*)(corr + ((size_t)b * HC + (size_t)chunk * ROWS_PER_CHUNK) * L);
    float4 acc = make_float4(0.f, 0.f, 0.f, 0.f);
    for (int r = 0; r < ROWS_PER_CHUNK; ++r) {
        float4 v = base[r * (L / 4) + tid];
        acc.x += v.x; acc.y += v.y; acc.z += v.z; acc.w += v.w;
    }
    ((float4*)(partial + (size_t)blk * L))[tid] = acc;
}

// ---------------------------------------------------------------------------
// Stage 2: mean_value[b][l] = sum of 32 partials / 512.
// grid = B*L/256 = 128 blocks. Consecutive threads -> consecutive l: coalesced.
// ---------------------------------------------------------------------------
__global__ __launch_bounds__(256) void mean_kernel(
    const float* __restrict__ partial, float* __restrict__ mean_value) {
    int gid = blockIdx.x * 256 + threadIdx.x;   // 0 .. B*L-1
    int b = gid / L;
    int l = gid - b * L;
    float s = 0.f;
    for (int c = 0; c < CHUNKS; ++c)
        s += partial[((size_t)b * CHUNKS + c) * L + l];
    mean_value[gid] = s * (1.0f / HC);
}

// ---------------------------------------------------------------------------
// Stage 3: column mean over b, top-6 via wave-shuffle argmax (tie-break:
// smaller index, matching lax.top_k), then per-batch softmax.
// Single block of 1024 threads (16 waves); 2 barriers per top-k round.
// ---------------------------------------------------------------------------
__global__ __launch_bounds__(1024) void topk_softmax_kernel(
    const float* __restrict__ mean_value,
    float* __restrict__ tmp_corr,       // [B][K]
    int* __restrict__ index_out) {      // [K]
    __shared__ float wval[16];
    __shared__ int   widx[16];
    __shared__ int   sel[K];
    int t = threadIdx.x;
    int lane = t & 63;
    int wave = t >> 6;

    float s = 0.f;
    for (int b = 0; b < B; ++b) s += mean_value[b * L + t];
    float cm = s * (1.0f / B);          // this thread's colmean value
    int   ci = t;

    for (int k = 0; k < K; ++k) {
        // wave-level argmax, tie-break smaller index
        float v = cm; int i = ci;
        #pragma unroll
        for (int off = 32; off >= 1; off >>= 1) {
            float v2 = __shfl_xor(v, off, 64);
            int   i2 = __shfl_xor(i, off, 64);
            if (v2 > v || (v2 == v && i2 < i)) { v = v2; i = i2; }
        }
        if (lane == 0) { wval[wave] = v; widx[wave] = i; }
        __syncthreads();
        if (wave == 0) {
            float v3 = (lane < 16) ? wval[lane] : -3.0e38f;
            int   i3 = (lane < 16) ? widx[lane] : 0x7fffffff;
            #pragma unroll
            for (int off = 8; off >= 1; off >>= 1) {
                float v2 = __shfl_xor(v3, off, 64);
                int   i2 = __shfl_xor(i3, off, 64);
                if (v2 > v3 || (v2 == v3 && i2 < i3)) { v3 = v2; i3 = i2; }
            }
            if (lane == 0) sel[k] = i3;
        }
        __syncthreads();
        if (ci == sel[k]) cm = -3.0e38f;   // remove from future rounds
    }

    if (t < K) index_out[t] = sel[t];
    if (t < B) {
        float w[K];
        float m = -3.0e38f;
        for (int k = 0; k < K; ++k) {
            w[k] = mean_value[t * L + sel[k]];
            m = fmaxf(m, w[k]);
        }
        float sum = 0.f;
        for (int k = 0; k < K; ++k) { w[k] = expf(w[k] - m); sum += w[k]; }
        float inv = 1.0f / sum;
        for (int k = 0; k < K; ++k) tmp_corr[t * K + k] = w[k] * inv;
    }
}

// ---------------------------------------------------------------------------
// Stage 4: out[b,h,c,l] = sum_k w[b,k] * values[b,h,c,(l+idx[k]) % L]
// One block per (b,h,c) row; row staged in LDS (4 KB) with float4.
// Each thread owns l = tid, tid+256, tid+512, tid+768: LDS reads are
// lane-consecutive (2 lanes/bank = conflict-free); stores are coalesced
// dword stores.
// ---------------------------------------------------------------------------
__global__ __launch_bounds__(256) void agg_kernel(
    const float* __restrict__ values,
    const float* __restrict__ tmp_corr,
    const int* __restrict__ index,
    float* __restrict__ out) {
    __shared__ float row[L];
    __shared__ float ws[K];
    __shared__ int   is[K];
    int blk = blockIdx.x;                  // 0 .. B*H*C-1
    int b = blk / HC;
    int tid = threadIdx.x;

    ((float4*)row)[tid] = ((const float4*)(values + (size_t)blk * L))[tid];
    if (tid < K) { ws[tid] = tmp_corr[b * K + tid]; is[tid] = index[tid]; }
    __syncthreads();

    float w[K]; int d[K];
    #pragma unroll
    for (int k = 0; k < K; ++k) { w[k] = ws[k]; d[k] = is[k]; }

    float* orow = out + (size_t)blk * L;
    #pragma unroll
    for (int off = 0; off < L; off += 256) {
        int l = tid + off;
        float acc = 0.f;
        #pragma unroll
        for (int k = 0; k < K; ++k)
            acc += w[k] * row[(l + d[k]) & (L - 1)];
        orow[l] = acc;
    }
}

// ---------------------------------------------------------------------------
extern "C" void kernel_launch(void* const* d_in, const int* in_sizes, int n_in,
                              void* d_out, int out_size, void* d_ws, size_t ws_size,
                              hipStream_t stream) {
    const float* values = (const float*)d_in[0];
    const float* corr   = (const float*)d_in[1];
    float* out = (float*)d_out;

    // workspace layout
    float* partial    = (float*)d_ws;                       // B*CHUNKS*L = 4 MiB
    float* mean_value = partial + (size_t)B * CHUNKS * L;   // B*L floats
    float* tmp_corr   = mean_value + (size_t)B * L;         // B*K floats
    int*   index      = (int*)(tmp_corr + B * K);           // K ints

    partial_sum_kernel<<<B * CHUNKS, 256, 0, stream>>>(corr, partial);
    mean_kernel<<<(B * L) / 256, 256, 0, stream>>>(partial, mean_value);
    topk_softmax_kernel<<<1, 1024, 0, stream>>>(mean_value, tmp_corr, index);
    agg_kernel<<<B * H * C, 256, 0, stream>>>(values, tmp_corr, index, out);
}

// Round 3
// 177.973 us; speedup vs baseline: 1.0414x; 1.0219x over previous
//
#include <hip/hip_runtime.h>
#include <math.h>

#define B 32
#define H 8
#define C 64
#define L 1024
#define HC (H * C)            // 512
#define K 6

#define SLICES 8
#define SLICE_L (L / SLICES)          // 128 l's per block
#define GROUPS 8                      // 32-lane groups per 256-thread block
#define ROWS_PER_GROUP (HC / GROUPS)  // 64 rows each

// ---------------------------------------------------------------------------
// Stage 1 (fused): mean_value[b][l] = mean over 512 (h,c) rows of corr.
// 256 blocks = 32 b x 8 l-slices. Each 32-lane group reads a 512 B contiguous
// float4 segment per row (fully coalesced), 64 rows per group, then a 4 KB
// LDS cross-group reduction. No intermediate global buffer.
// ---------------------------------------------------------------------------
__global__ __launch_bounds__(256) void mean_value_kernel(
    const float* __restrict__ corr, float* __restrict__ mean_value) {
    __shared__ float sacc[GROUPS * SLICE_L];   // 4 KB
    int blk = blockIdx.x;                      // 0..255
    int b = blk / SLICES;
    int s = blk % SLICES;
    int t = threadIdx.x;
    int g = t >> 5;                            // group 0..7
    int j = t & 31;                            // lane-in-group

    const float4* base =
        (const float4*)(corr + (size_t)b * HC * L + s * SLICE_L);
    float4 acc = make_float4(0.f, 0.f, 0.f, 0.f);
    #pragma unroll 8
    for (int i = 0; i < ROWS_PER_GROUP; ++i) {
        int r = g + GROUPS * i;                // rows g, g+8, ...
        float4 v = base[(size_t)r * (L / 4) + j];
        acc.x += v.x; acc.y += v.y; acc.z += v.z; acc.w += v.w;
    }
    ((float4*)sacc)[g * (SLICE_L / 4) + j] = acc;
    __syncthreads();

    if (t < SLICE_L) {
        float m = 0.f;
        #pragma unroll
        for (int g2 = 0; g2 < GROUPS; ++g2) m += sacc[g2 * SLICE_L + t];
        mean_value[b * L + s * SLICE_L + t] = m * (1.0f / HC);
    }
}

// ---------------------------------------------------------------------------
// Stage 2: column mean over b, top-6 via wave-shuffle argmax (tie-break:
// smaller index, matching lax.top_k), then per-batch softmax.
// Single block of 1024 threads (16 waves); 2 barriers per top-k round.
// ---------------------------------------------------------------------------
__global__ __launch_bounds__(1024) void topk_softmax_kernel(
    const float* __restrict__ mean_value,
    float* __restrict__ tmp_corr,       // [B][K]
    int* __restrict__ index_out) {      // [K]
    __shared__ float wval[16];
    __shared__ int   widx[16];
    __shared__ int   sel[K];
    int t = threadIdx.x;
    int lane = t & 63;
    int wave = t >> 6;

    float s = 0.f;
    for (int b = 0; b < B; ++b) s += mean_value[b * L + t];
    float cm = s * (1.0f / B);          // this thread's colmean value
    int   ci = t;

    for (int k = 0; k < K; ++k) {
        // wave-level argmax, tie-break smaller index
        float v = cm; int i = ci;
        #pragma unroll
        for (int off = 32; off >= 1; off >>= 1) {
            float v2 = __shfl_xor(v, off, 64);
            int   i2 = __shfl_xor(i, off, 64);
            if (v2 > v || (v2 == v && i2 < i)) { v = v2; i = i2; }
        }
        if (lane == 0) { wval[wave] = v; widx[wave] = i; }
        __syncthreads();
        if (wave == 0) {
            float v3 = (lane < 16) ? wval[lane] : -3.0e38f;
            int   i3 = (lane < 16) ? widx[lane] : 0x7fffffff;
            #pragma unroll
            for (int off = 8; off >= 1; off >>= 1) {
                float v2 = __shfl_xor(v3, off, 64);
                int   i2 = __shfl_xor(i3, off, 64);
                if (v2 > v3 || (v2 == v3 && i2 < i3)) { v3 = v2; i3 = i2; }
            }
            if (lane == 0) sel[k] = i3;
        }
        __syncthreads();
        if (ci == sel[k]) cm = -3.0e38f;   // remove from future rounds
    }

    if (t < K) index_out[t] = sel[t];
    if (t < B) {
        float w[K];
        float m = -3.0e38f;
        for (int k = 0; k < K; ++k) {
            w[k] = mean_value[t * L + sel[k]];
            m = fmaxf(m, w[k]);
        }
        float sum = 0.f;
        for (int k = 0; k < K; ++k) { w[k] = expf(w[k] - m); sum += w[k]; }
        float inv = 1.0f / sum;
        for (int k = 0; k < K; ++k) tmp_corr[t * K + k] = w[k] * inv;
    }
}

// ---------------------------------------------------------------------------
// Stage 3: out[b,h,c,l] = sum_k w[b,k] * values[b,h,c,(l+idx[k]) % L]
// One block per (b,h,c) row; row staged in LDS (4 KB) with float4.
// Each thread owns l = tid, tid+256, tid+512, tid+768: LDS reads are
// lane-consecutive (2 lanes/bank = conflict-free); stores are coalesced
// dword stores.
// ---------------------------------------------------------------------------
__global__ __launch_bounds__(256) void agg_kernel(
    const float* __restrict__ values,
    const float* __restrict__ tmp_corr,
    const int* __restrict__ index,
    float* __restrict__ out) {
    __shared__ float row[L];
    __shared__ float ws[K];
    __shared__ int   is[K];
    int blk = blockIdx.x;                  // 0 .. B*H*C-1
    int b = blk / HC;
    int tid = threadIdx.x;

    ((float4*)row)[tid] = ((const float4*)(values + (size_t)blk * L))[tid];
    if (tid < K) { ws[tid] = tmp_corr[b * K + tid]; is[tid] = index[tid]; }
    __syncthreads();

    float w[K]; int d[K];
    #pragma unroll
    for (int k = 0; k < K; ++k) { w[k] = ws[k]; d[k] = is[k]; }

    float* orow = out + (size_t)blk * L;
    #pragma unroll
    for (int off = 0; off < L; off += 256) {
        int l = tid + off;
        float acc = 0.f;
        #pragma unroll
        for (int k = 0; k < K; ++k)
            acc += w[k] * row[(l + d[k]) & (L - 1)];
        orow[l] = acc;
    }
}

// ---------------------------------------------------------------------------
extern "C" void kernel_launch(void* const* d_in, const int* in_sizes, int n_in,
                              void* d_out, int out_size, void* d_ws, size_t ws_size,
                              hipStream_t stream) {
    const float* values = (const float*)d_in[0];
    const float* corr   = (const float*)d_in[1];
    float* out = (float*)d_out;

    // workspace layout
    float* mean_value = (float*)d_ws;                       // B*L floats
    float* tmp_corr   = mean_value + (size_t)B * L;         // B*K floats
    int*   index      = (int*)(tmp_corr + B * K);           // K ints

    mean_value_kernel<<<B * SLICES, 256, 0, stream>>>(corr, mean_value);
    topk_softmax_kernel<<<1, 1024, 0, stream>>>(mean_value, tmp_corr, index);
    agg_kernel<<<B * H * C, 256, 0, stream>>>(values, tmp_corr, index, out);
}